// Round 1
// baseline (3441.116 us; speedup 1.0000x reference)
//
#include <hip/hip_runtime.h>
#include <hip/hip_bf16.h>

#define ATOM_FDIM 133
#define BOND_FDIM 147
#define HIDDEN    300
#define N_ATOMS   100000
#define N_BONDS   200000
#define MAX_NB    6
#define N_MOLS    4000

typedef __hip_bfloat16 bf16;

__device__ __forceinline__ float b2f(bf16 x) { return __bfloat162float(x); }
__device__ __forceinline__ bf16  f2b(float x) { return __float2bfloat16(x); }

#define BM 64
#define BN 64
#define BK 16

// MODE 0: A = f_bonds [M x 147] f32.  out0 = inp (bf16), out1 = relu(inp) (bf16)
// MODE 1: A[b][k] = a_msg[b2a[b]][k] - msg_cur[b2revb[b]][k] (bf16 gathers).
//         out0 = relu(inp + A@W) (bf16)
// MODE 2: A[a][k] = k<133 ? f_atoms[a][k] : a_msg[a][k-133].
//         out0 = relu(A@W + bias) (bf16)
template <int MODE>
__global__ __launch_bounds__(256) void gemm_k(
    const float* __restrict__ Af32,    // mode0: f_bonds; mode2: f_atoms
    const bf16*  __restrict__ a_msg,   // mode1/2
    const bf16*  __restrict__ msg_cur, // mode1
    const int*   __restrict__ b2a,     // mode1
    const int*   __restrict__ b2revb,  // mode1
    const float* __restrict__ W,       // [K x 300] row-major
    const float* __restrict__ bias,    // mode2
    const bf16*  __restrict__ inp,     // mode1
    bf16* __restrict__ out0,
    bf16* __restrict__ out1,           // mode0 only
    int M, int K)
{
    const int N = HIDDEN;
    __shared__ float As[BK][BM + 4];   // +4 pad: keeps float4 rows 16B-aligned, banks spread
    __shared__ float Ws[BK][BN];

    const int n0 = blockIdx.x * BN;
    const int m0 = blockIdx.y * BM;
    const int t  = threadIdx.x;
    const int tx = t % 16;             // col group
    const int ty = t / 16;             // row group

    float acc[4][4] = {};

    for (int k0 = 0; k0 < K; k0 += BK) {
        // ---- stage W tile: BK x BN, coalesced 64-wide ----
        {
            const int c = t % 64;
            const int r = t / 64;      // 0..3
            #pragma unroll
            for (int rr = r; rr < BK; rr += 4) {
                int kk = k0 + rr, n = n0 + c;
                Ws[rr][c] = (kk < K && n < N) ? W[(size_t)kk * N + n] : 0.f;
            }
        }
        // ---- stage A tile (transposed into LDS): BM rows x BK k ----
        {
            const int c = t % 16;      // k offset
            const int r = t / 16;      // row 0..15, strided
            #pragma unroll
            for (int rr = r; rr < BM; rr += 16) {
                const int row = m0 + rr;
                const int k   = k0 + c;
                float v = 0.f;
                if (row < M && k < K) {
                    if (MODE == 0) {
                        v = Af32[(size_t)row * BOND_FDIM + k];
                    } else if (MODE == 1) {
                        const int ia = b2a[row];
                        const int ir = b2revb[row];
                        v = b2f(a_msg[(size_t)ia * HIDDEN + k]) -
                            b2f(msg_cur[(size_t)ir * HIDDEN + k]);
                    } else {
                        v = (k < ATOM_FDIM)
                              ? Af32[(size_t)row * ATOM_FDIM + k]
                              : b2f(a_msg[(size_t)row * HIDDEN + (k - ATOM_FDIM)]);
                    }
                }
                As[c][rr] = v;
            }
        }
        __syncthreads();

        // ---- compute: 4x4 micro-tile, float4 LDS fragment loads ----
        #pragma unroll
        for (int kk = 0; kk < BK; ++kk) {
            const float4 av = *reinterpret_cast<const float4*>(&As[kk][ty * 4]);
            const float4 bv = *reinterpret_cast<const float4*>(&Ws[kk][tx * 4]);
            const float a[4] = {av.x, av.y, av.z, av.w};
            const float b[4] = {bv.x, bv.y, bv.z, bv.w};
            #pragma unroll
            for (int i = 0; i < 4; ++i)
                #pragma unroll
                for (int j = 0; j < 4; ++j)
                    acc[i][j] += a[i] * b[j];
        }
        __syncthreads();
    }

    // ---- epilogue ----
    #pragma unroll
    for (int i = 0; i < 4; ++i) {
        const int row = m0 + ty * 4 + i;
        if (row >= M) continue;
        #pragma unroll
        for (int j = 0; j < 4; ++j) {
            const int n = n0 + tx * 4 + j;
            if (n >= N) continue;
            const size_t o = (size_t)row * N + n;
            float v = acc[i][j];
            if (MODE == 0) {
                out0[o] = f2b(v);
                out1[o] = f2b(fmaxf(v, 0.f));
            } else if (MODE == 1) {
                out0[o] = f2b(fmaxf(b2f(inp[o]) + v, 0.f));
            } else {
                out0[o] = f2b(fmaxf(v + bias[n], 0.f));
            }
        }
    }
}

// a_msg[a][h] = sum_{j<6} msg[a2b[a][j]][h]   (one wave per atom)
__global__ __launch_bounds__(256) void atom_agg_k(const bf16* __restrict__ msg,
                                                  const int*  __restrict__ a2b,
                                                  bf16* __restrict__ a_msg)
{
    const int wave = threadIdx.x / 64;
    const int lane = threadIdx.x % 64;
    const int a = blockIdx.x * 4 + wave;
    if (a >= N_ATOMS) return;
    int idx[MAX_NB];
    #pragma unroll
    for (int j = 0; j < MAX_NB; ++j) idx[j] = a2b[a * MAX_NB + j];
    for (int h = lane; h < HIDDEN; h += 64) {
        float s = 0.f;
        #pragma unroll
        for (int j = 0; j < MAX_NB; ++j) s += b2f(msg[(size_t)idx[j] * HIDDEN + h]);
        a_msg[(size_t)a * HIDDEN + h] = f2b(s);
    }
}

// per-mol mean over sorted atom2mol (binary-searched range), no atomics
__global__ __launch_bounds__(256) void mol_pool_k(const bf16* __restrict__ ah,
                                                  const int*  __restrict__ a2m,
                                                  float* __restrict__ out)
{
    const int m = blockIdx.x;
    int lo, hi;
    {
        int l = 0, r = N_ATOMS;
        while (l < r) { int mid = (l + r) >> 1; if (a2m[mid] < m) l = mid + 1; else r = mid; }
        lo = l;
    }
    {
        int l = lo, r = N_ATOMS;
        while (l < r) { int mid = (l + r) >> 1; if (a2m[mid] < m + 1) l = mid + 1; else r = mid; }
        hi = l;
    }
    const float inv = 1.0f / (float)((hi - lo) > 1 ? (hi - lo) : 1);
    for (int h = threadIdx.x; h < HIDDEN; h += 256) {
        float s = 0.f;
        for (int a = lo; a < hi; ++a) s += b2f(ah[(size_t)a * HIDDEN + h]);
        out[(size_t)m * HIDDEN + h] = s * inv;
    }
}

extern "C" void kernel_launch(void* const* d_in, const int* in_sizes, int n_in,
                              void* d_out, int out_size, void* d_ws, size_t ws_size,
                              hipStream_t stream)
{
    const float* f_atoms  = (const float*)d_in[0];
    const float* f_bonds  = (const float*)d_in[1];
    const int*   a2b      = (const int*)d_in[2];
    const int*   b2a      = (const int*)d_in[3];
    const int*   b2revb   = (const int*)d_in[4];
    const int*   atom2mol = (const int*)d_in[5];
    const float* W_i      = (const float*)d_in[6];
    const float* W_h      = (const float*)d_in[7];
    const float* W_o_w    = (const float*)d_in[8];
    const float* W_o_b    = (const float*)d_in[9];
    float* out = (float*)d_out;

    char* ws = (char*)d_ws;
    const size_t S_MSG  = (size_t)N_BONDS * HIDDEN * sizeof(bf16);  // 120 MB
    const size_t S_AMSG = (size_t)N_ATOMS * HIDDEN * sizeof(bf16);  //  60 MB
    bf16* inp  = (bf16*)(ws);
    bf16* msgA = (bf16*)(ws + S_MSG);
    bf16* msgB = (bf16*)(ws + 2 * S_MSG);
    bf16* amsg = (bf16*)(ws + 3 * S_MSG);
    // atom_hiddens aliases msgB: after the final atom_agg (reads msgA), msgB is dead.
    bf16* ah   = msgB;

    const dim3 blk(256);
    const dim3 gB((HIDDEN + BN - 1) / BN, (N_BONDS + BM - 1) / BM);  // 5 x 3125
    const dim3 gA((HIDDEN + BN - 1) / BN, (N_ATOMS + BM - 1) / BM);  // 5 x 1563

    // inp = f_bonds @ W_i ; msgA = relu(inp)
    gemm_k<0><<<gB, blk, 0, stream>>>(f_bonds, nullptr, nullptr, nullptr, nullptr,
                                      W_i, nullptr, nullptr, inp, msgA,
                                      N_BONDS, BOND_FDIM);

    bf16* cur = msgA;
    bf16* nxt = msgB;
    for (int it = 0; it < 2; ++it) {   // DEPTH-1 iterations
        atom_agg_k<<<dim3((N_ATOMS + 3) / 4), blk, 0, stream>>>(cur, a2b, amsg);
        gemm_k<1><<<gB, blk, 0, stream>>>(nullptr, amsg, cur, b2a, b2revb,
                                          W_h, nullptr, inp, nxt, nullptr,
                                          N_BONDS, HIDDEN);
        bf16* tmp = cur; cur = nxt; nxt = tmp;
    }
    // final: cur == msgA (A -> B -> A)
    atom_agg_k<<<dim3((N_ATOMS + 3) / 4), blk, 0, stream>>>(cur, a2b, amsg);
    gemm_k<2><<<gA, blk, 0, stream>>>(f_atoms, amsg, nullptr, nullptr, nullptr,
                                      W_o_w, W_o_b, nullptr, ah, nullptr,
                                      N_ATOMS, ATOM_FDIM + HIDDEN);
    mol_pool_k<<<dim3(N_MOLS), blk, 0, stream>>>(ah, atom2mol, out);
}

// Round 2
// 1128.820 us; speedup vs baseline: 3.0484x; 3.0484x over previous
//
#include <hip/hip_runtime.h>
#include <stdint.h>

#define ATOM_FDIM 133
#define BOND_FDIM 147
#define HIDDEN    300
#define N_ATOMS   100000
#define N_BONDS   200000
#define MAX_NB    6
#define N_MOLS    4000

#define NPAD 320      // padded N for all GEMMs
#define KP_I 160      // padded K for W_i GEMM (147)
#define KP_H 320      // padded K for W_h GEMM (300)
#define KP_O 448      // padded K for W_o GEMM (433)
#define LDM  304      // msg row stride in elems (16B-aligned rows: 608B)

typedef unsigned short u16;
typedef short bf16x8 __attribute__((ext_vector_type(8)));   // 8 bf16 in 4 VGPRs
typedef float f32x4 __attribute__((ext_vector_type(4)));

__device__ __forceinline__ u16 f2bu(float f) {            // f32 -> bf16 (RNE)
    unsigned u = __float_as_uint(f);
    u += 0x7FFFu + ((u >> 16) & 1u);
    return (u16)(u >> 16);
}
__device__ __forceinline__ float bu2f(u16 b) { return __uint_as_float(((unsigned)b) << 16); }

#define AS1 __attribute__((address_space(1)))
#define AS3 __attribute__((address_space(3)))
__device__ __forceinline__ void gl_lds16(const void* g, void* l) {
    __builtin_amdgcn_global_load_lds((const AS1 void*)g, (AS3 void*)l, 16, 0, 0);
}

// ---------------- dense bf16 MFMA GEMM:  C[M][300] = A[M][Kp] @ Wt[320][Kp]^T ----------
// EPI 0: out0=inp (raw), out1=relu  | EPI 1: out0=raw  | EPI 2: out0=relu(v+bias)
template <int EPI>
__global__ __launch_bounds__(256) void mm_k(
    const u16* __restrict__ A, int lda,
    const u16* __restrict__ Wt, int ldw,
    const float* __restrict__ bias,
    u16* __restrict__ out0, int ldo0,
    u16* __restrict__ out1, int ldo1,
    int M, int Kp)
{
    __shared__ __align__(16) u16 As[256 * 32];   // 16 KB
    __shared__ __align__(16) u16 Bs[64 * 32];    //  4 KB

    const int t    = threadIdx.x;
    const int lane = t & 63, wid = t >> 6;
    const int m0   = blockIdx.y * 256, n0 = blockIdx.x * 64;

    // staging addresses: chunk = 16 rows x 32k (1 KB); lane covers row=lane>>2, seg=(lane&3)*16B
    const int l4 = lane >> 2;
    const int s16 = (lane & 3) * 16;
    size_t offA[4];
    #pragma unroll
    for (int i = 0; i < 4; ++i) {
        int r = m0 + wid * 64 + i * 16 + l4;
        if (r > M - 1) r = M - 1;                 // clamp: no row padding needed
        offA[i] = (size_t)r * lda * 2 + s16;
    }
    const size_t offB = (size_t)(n0 + wid * 16 + l4) * ldw * 2 + s16;

    char* ldsA = (char*)As + (size_t)wid * 4096;
    char* ldsB = (char*)Bs + (size_t)wid * 1024;

    // fragment read offsets (elems): A row = wid*64+m*16+(lane&15), k = (lane>>4)*8
    const int fl = lane & 15, fh = lane >> 4;
    const int aoff = (wid * 64 + fl) * 32 + fh * 8;
    const int boff = fl * 32 + fh * 8;

    f32x4 acc[4][4] = {};

    for (int k0 = 0; k0 < Kp; k0 += 32) {
        const size_t kb = (size_t)k0 * 2;
        #pragma unroll
        for (int i = 0; i < 4; ++i)
            gl_lds16((const char*)A + (offA[i] + kb), ldsA + i * 1024);
        gl_lds16((const char*)Wt + (offB + kb), ldsB);
        __syncthreads();                           // compiler drains vmcnt before barrier

        bf16x8 af[4], bfv[4];
        #pragma unroll
        for (int m = 0; m < 4; ++m)
            af[m] = *reinterpret_cast<const bf16x8*>(&As[aoff + m * 512]);
        #pragma unroll
        for (int n = 0; n < 4; ++n)
            bfv[n] = *reinterpret_cast<const bf16x8*>(&Bs[boff + n * 512]);
        #pragma unroll
        for (int m = 0; m < 4; ++m)
            #pragma unroll
            for (int n = 0; n < 4; ++n)
                acc[m][n] = __builtin_amdgcn_mfma_f32_16x16x32_bf16(af[m], bfv[n], acc[m][n], 0, 0, 0);
        __syncthreads();
    }

    // epilogue: C/D layout col=lane&15, row=(lane>>4)*4+reg
    #pragma unroll
    for (int m = 0; m < 4; ++m) {
        #pragma unroll
        for (int r = 0; r < 4; ++r) {
            const int row = m0 + wid * 64 + m * 16 + fh * 4 + r;
            if (row >= M) continue;
            #pragma unroll
            for (int n = 0; n < 4; ++n) {
                const int col = n0 + n * 16 + fl;
                if (col >= HIDDEN) continue;
                const float v = acc[m][n][r];
                if (EPI == 0) {
                    out0[(size_t)row * ldo0 + col] = f2bu(v);
                    out1[(size_t)row * ldo1 + col] = f2bu(fmaxf(v, 0.f));
                } else if (EPI == 1) {
                    out0[(size_t)row * ldo0 + col] = f2bu(v);
                } else {
                    out0[(size_t)row * ldo0 + col] = f2bu(fmaxf(v + bias[col], 0.f));
                }
            }
        }
    }
}

// ---- weight transpose+convert: Wt[n][k] = (n<300 && k<Ks) ? W[k][n] : 0 ----
__global__ __launch_bounds__(256) void wconv_k(const float* __restrict__ W, int Ks, int Kp,
                                               u16* __restrict__ Wt)
{
    const int id = blockIdx.x * 256 + threadIdx.x;
    if (id >= NPAD * Kp) return;
    const int n = id / Kp, k = id - n * Kp;
    const float v = (n < HIDDEN && k < Ks) ? W[(size_t)k * HIDDEN + n] : 0.f;
    Wt[id] = f2bu(v);
}

// ---- f_bonds f32 -> bf16 padded [200000][160] ----
__global__ __launch_bounds__(256) void fbconv_k(const float* __restrict__ fb, u16* __restrict__ dst)
{
    const int id = blockIdx.x * 256 + threadIdx.x;
    if (id >= N_BONDS * KP_I) return;
    const int r = id / KP_I, k = id - r * KP_I;
    dst[id] = f2bu(k < BOND_FDIM ? fb[(size_t)r * BOND_FDIM + k] : 0.f);
}

// ---- dst[a][0:300] = sum_j src[a2b[a][j]][0:300]   (8B chunks) ----
__global__ __launch_bounds__(256) void agg_k(const u16* __restrict__ src, int ld,
                                             const int* __restrict__ a2b, u16* __restrict__ dst)
{
    const int c = blockIdx.x * 256 + threadIdx.x;
    if (c >= N_ATOMS * 75) return;
    const int a = c / 75, q = c - a * 75;
    const int h = q * 4;
    const int* nb = a2b + (size_t)a * MAX_NB;
    float s0 = 0.f, s1 = 0.f, s2 = 0.f, s3 = 0.f;
    #pragma unroll
    for (int j = 0; j < MAX_NB; ++j) {
        const int r = nb[j];
        union { uint2 u; u16 s[4]; } x;
        x.u = *(const uint2*)(src + (size_t)r * ld + h);
        s0 += bu2f(x.s[0]); s1 += bu2f(x.s[1]); s2 += bu2f(x.s[2]); s3 += bu2f(x.s[3]);
    }
    union { uint2 u; u16 s[4]; } o;
    o.s[0] = f2bu(s0); o.s[1] = f2bu(s1); o.s[2] = f2bu(s2); o.s[3] = f2bu(s3);
    *(uint2*)(dst + (size_t)a * 300 + h) = o.u;
}

// ---- msg[b] = relu(inp[b] + aY[b2a[b]] - Y[b2revb[b]]) ----
__global__ __launch_bounds__(256) void comb_k(const u16* __restrict__ inp,
                                              const u16* __restrict__ aY,
                                              const u16* __restrict__ Y,
                                              const int* __restrict__ b2a,
                                              const int* __restrict__ b2revb,
                                              u16* __restrict__ msg)
{
    const int c = blockIdx.x * 256 + threadIdx.x;
    if (c >= N_BONDS * 75) return;
    const int b = c / 75, q = c - b * 75;
    const int h = q * 4;
    const int ia = b2a[b], ir = b2revb[b];
    union { uint2 u; u16 s[4]; } xi, xa, xy, o;
    xi.u = *(const uint2*)(inp + (size_t)b * 300 + h);
    xa.u = *(const uint2*)(aY + (size_t)ia * 300 + h);
    xy.u = *(const uint2*)(Y + (size_t)ir * 300 + h);
    #pragma unroll
    for (int j = 0; j < 4; ++j)
        o.s[j] = f2bu(fmaxf(bu2f(xi.s[j]) + bu2f(xa.s[j]) - bu2f(xy.s[j]), 0.f));
    *(uint2*)(msg + (size_t)b * LDM + h) = o.u;
}

// ---- concat[a][k] : k<133 f_atoms | k<433 amsg | 0 ----
__global__ __launch_bounds__(256) void concat_k(const float* __restrict__ fa,
                                                const u16* __restrict__ amsg,
                                                u16* __restrict__ dst)
{
    const int id = blockIdx.x * 256 + threadIdx.x;
    if (id >= N_ATOMS * KP_O) return;
    const int a = id / KP_O, k = id - a * KP_O;
    float v;
    if (k < ATOM_FDIM)                     v = fa[(size_t)a * ATOM_FDIM + k];
    else if (k < ATOM_FDIM + HIDDEN)       v = bu2f(amsg[(size_t)a * 300 + (k - ATOM_FDIM)]);
    else                                   v = 0.f;
    dst[id] = f2bu(v);
}

// ---- per-mol mean over sorted atom2mol ----
__global__ __launch_bounds__(320) void pool_k(const u16* __restrict__ ah,
                                              const int* __restrict__ a2m,
                                              float* __restrict__ out)
{
    const int m = blockIdx.x;
    int lo, hi;
    { int l = 0, r = N_ATOMS;
      while (l < r) { int mid = (l + r) >> 1; if (a2m[mid] < m) l = mid + 1; else r = mid; }
      lo = l; }
    { int l = lo, r = N_ATOMS;
      while (l < r) { int mid = (l + r) >> 1; if (a2m[mid] < m + 1) l = mid + 1; else r = mid; }
      hi = l; }
    const float inv = 1.0f / (float)((hi - lo) > 1 ? (hi - lo) : 1);
    const int h = threadIdx.x;
    if (h >= HIDDEN) return;
    float s = 0.f;
    for (int a = lo; a < hi; ++a) s += bu2f(ah[(size_t)a * 300 + h]);
    out[(size_t)m * HIDDEN + h] = s * inv;
}

extern "C" void kernel_launch(void* const* d_in, const int* in_sizes, int n_in,
                              void* d_out, int out_size, void* d_ws, size_t ws_size,
                              hipStream_t stream)
{
    const float* f_atoms  = (const float*)d_in[0];
    const float* f_bonds  = (const float*)d_in[1];
    const int*   a2b      = (const int*)d_in[2];
    const int*   b2a      = (const int*)d_in[3];
    const int*   b2revb   = (const int*)d_in[4];
    const int*   atom2mol = (const int*)d_in[5];
    const float* W_i      = (const float*)d_in[6];
    const float* W_h      = (const float*)d_in[7];
    const float* W_o_w    = (const float*)d_in[8];
    const float* W_o_b    = (const float*)d_in[9];
    float* out = (float*)d_out;

    // ---- workspace layout (all bf16 as u16) ----
    char* p = (char*)d_ws;
    auto alloc = [&](size_t bytes) { char* r = p; p += (bytes + 255) & ~(size_t)255; return r; };
    u16* inp = (u16*)alloc((size_t)N_BONDS * 300 * 2);          // 120.0 MB, stride 300
    u16* msg = (u16*)alloc(((size_t)N_BONDS + 1) * LDM * 2);    // 121.6 MB, stride 304 (+1 row for k-spill)
    u16* Yb  = (u16*)alloc((size_t)N_BONDS * 300 * 2);          // 120.0 MB; also hosts fb16 / concat
    u16* aY  = (u16*)alloc((size_t)N_ATOMS * 300 * 2);          //  60.0 MB
    u16* Wti = (u16*)alloc((size_t)NPAD * KP_I * 2);
    u16* Wth = (u16*)alloc((size_t)NPAD * KP_H * 2);
    u16* Wto = (u16*)alloc((size_t)NPAD * KP_O * 2);
    if ((size_t)(p - (char*)d_ws) > ws_size) return;            // visible failure if ws too small

    u16* fb16   = Yb;   // [200000][160], dead before first Y write
    u16* concat = Yb;   // [100000][448], built after Y dead
    u16* ah     = msg;  // [100000][300], msg dead after final agg

    const dim3 blk(256);
    auto g1 = [](long long n) { return dim3((unsigned)((n + 255) / 256)); };
    const dim3 gB(5, (N_BONDS + 255) / 256);   // 5 x 782
    const dim3 gA(5, (N_ATOMS + 255) / 256);   // 5 x 391

    // weights -> transposed bf16 panels
    wconv_k<<<g1((long long)NPAD * KP_I), blk, 0, stream>>>(W_i, BOND_FDIM, KP_I, Wti);
    wconv_k<<<g1((long long)NPAD * KP_H), blk, 0, stream>>>(W_h, HIDDEN, KP_H, Wth);
    wconv_k<<<g1((long long)NPAD * KP_O), blk, 0, stream>>>(W_o_w, ATOM_FDIM + HIDDEN, KP_O, Wto);
    fbconv_k<<<g1((long long)N_BONDS * KP_I), blk, 0, stream>>>(f_bonds, fb16);

    // inp = f_bonds @ W_i ; msg = relu(inp)
    mm_k<0><<<gB, blk, 0, stream>>>(fb16, KP_I, Wti, KP_I, nullptr,
                                    inp, 300, msg, LDM, N_BONDS, KP_I);

    for (int it = 0; it < 2; ++it) {   // DEPTH-1
        // Y = msg @ W_h
        mm_k<1><<<gB, blk, 0, stream>>>(msg, LDM, Wth, KP_H, nullptr,
                                        Yb, 300, nullptr, 0, N_BONDS, KP_H);
        // aY[a] = sum_j Y[a2b[a][j]]
        agg_k<<<g1((long long)N_ATOMS * 75), blk, 0, stream>>>(Yb, 300, a2b, aY);
        // msg = relu(inp + aY[b2a] - Y[b2revb])   (in-place safe: reads inp/aY/Y only)
        comb_k<<<g1((long long)N_BONDS * 75), blk, 0, stream>>>(inp, aY, Yb, b2a, b2revb, msg);
    }

    // final atom aggregation on msg, then concat and output GEMM
    agg_k<<<g1((long long)N_ATOMS * 75), blk, 0, stream>>>(msg, LDM, a2b, aY);
    concat_k<<<g1((long long)N_ATOMS * KP_O), blk, 0, stream>>>(f_atoms, aY, concat);
    mm_k<2><<<gA, blk, 0, stream>>>(concat, KP_O, Wto, KP_O, W_o_b,
                                    ah, 300, nullptr, 0, N_ATOMS, KP_O);
    pool_k<<<dim3(N_MOLS), dim3(320), 0, stream>>>(ah, atom2mol, out);
}

// Round 3
// 1013.853 us; speedup vs baseline: 3.3941x; 1.1134x over previous
//
#include <hip/hip_runtime.h>
#include <stdint.h>

#define ATOM_FDIM 133
#define BOND_FDIM 147
#define HIDDEN    300
#define N_ATOMS   100000
#define N_BONDS   200000
#define MAX_NB    6
#define N_MOLS    4000

#define NPAD 320      // padded N for all GEMMs
#define KP_I 160      // padded K for W_i GEMM (147)
#define KP_H 320      // padded K for W_h GEMM (300)
#define KP_O 448      // padded K for W_o GEMM (433)
#define LDA  304      // activation row stride in elems (608B, 16B-aligned)
#define CPR  38       // uint4 chunks per activation row (304/8)

typedef unsigned short u16;
typedef short bf16x8 __attribute__((ext_vector_type(8)));
typedef float f32x4 __attribute__((ext_vector_type(4)));

__device__ __forceinline__ u16 f2bu(float f) {            // f32 -> bf16 (RNE)
    unsigned u = __float_as_uint(f);
    u += 0x7FFFu + ((u >> 16) & 1u);
    return (u16)(u >> 16);
}
__device__ __forceinline__ float bu2f(u16 b) { return __uint_as_float(((unsigned)b) << 16); }

#define AS1 __attribute__((address_space(1)))
#define AS3 __attribute__((address_space(3)))
__device__ __forceinline__ void gl_lds16(const void* g, void* l) {
    __builtin_amdgcn_global_load_lds((const AS1 void*)g, (AS3 void*)l, 16, 0, 0);
}

// ------------- dense bf16 MFMA GEMM, full-N tile: C[64 x 300] per block ---------------
// Block: 64 rows x 320 cols. 4 waves 2x2; wave = 32 rows x 160 cols = 2x10 frags.
// LDS is subtile-ordered so fragment reads are contiguous lane*16B (conflict-free):
//   A chunk c (16 rows): slot (kseg*16 + row) <- staged by lane l from global
//   (row = base + (l&15), kseg = l>>4). Same for B (Wt rows = output cols).
// EPI 0: out0=raw, out1=relu | EPI 1: out0=raw | EPI 2: out0=relu(v+bias)
template <int EPI>
__global__ __launch_bounds__(256) void mm_k(
    const u16* __restrict__ A, int lda,
    const u16* __restrict__ Wt, int ldw,
    const float* __restrict__ bias,
    u16* __restrict__ out0, int ldo0,
    u16* __restrict__ out1, int ldo1,
    int M, int Kp)
{
    __shared__ __align__(16) u16 As[64 * 32];    //  4 KB, 4 chunks of 1 KB
    __shared__ __align__(16) u16 Bs[320 * 32];   // 20 KB, 20 chunks of 1 KB

    const int t    = threadIdx.x;
    const int lane = t & 63, wid = t >> 6;
    const int fl   = lane & 15, fh = lane >> 4;
    const int m0   = blockIdx.x * 64;
    const int wr   = wid >> 1, wc = wid & 1;

    // staging sources (pre-swizzled so LDS ends up fragment-ordered)
    int arow = m0 + wid * 16 + fl;
    if (arow > M - 1) arow = M - 1;
    const unsigned offA = (unsigned)arow * (unsigned)lda * 2u + (unsigned)fh * 16u;
    unsigned offB[5];
    #pragma unroll
    for (int j = 0; j < 5; ++j) {
        const int c = wid + 4 * j;               // B chunk id 0..19
        offB[j] = (unsigned)(c * 16 + fl) * (unsigned)ldw * 2u + (unsigned)fh * 16u;
    }
    char* ldsA = (char*)As + wid * 1024;

    f32x4 acc[2][10] = {};

    for (int k0 = 0; k0 < Kp; k0 += 32) {
        const unsigned kb = (unsigned)k0 * 2u;
        gl_lds16((const char*)A + (size_t)(offA + kb), ldsA);
        #pragma unroll
        for (int j = 0; j < 5; ++j)
            gl_lds16((const char*)Wt + (size_t)(offB[j] + kb), (char*)Bs + (wid + 4 * j) * 1024);
        __syncthreads();

        bf16x8 af[2], bfv[10];
        #pragma unroll
        for (int m = 0; m < 2; ++m)
            af[m] = *reinterpret_cast<const bf16x8*>(&As[(wr * 2 + m) * 512 + lane * 8]);
        #pragma unroll
        for (int n = 0; n < 10; ++n)
            bfv[n] = *reinterpret_cast<const bf16x8*>(&Bs[(wc * 10 + n) * 512 + lane * 8]);
        #pragma unroll
        for (int m = 0; m < 2; ++m)
            #pragma unroll
            for (int n = 0; n < 10; ++n)
                acc[m][n] = __builtin_amdgcn_mfma_f32_16x16x32_bf16(af[m], bfv[n], acc[m][n], 0, 0, 0);
        __syncthreads();
    }

    // epilogue: C/D col=lane&15, row=(lane>>4)*4+reg
    #pragma unroll
    for (int m = 0; m < 2; ++m) {
        #pragma unroll
        for (int r = 0; r < 4; ++r) {
            const int row = m0 + wr * 32 + m * 16 + fh * 4 + r;
            if (row >= M) continue;
            #pragma unroll
            for (int n = 0; n < 10; ++n) {
                const int col = wc * 160 + n * 16 + fl;
                if (col >= HIDDEN) continue;
                const float v = acc[m][n][r];
                if (EPI == 0) {
                    out0[(size_t)row * ldo0 + col] = f2bu(v);
                    out1[(size_t)row * ldo1 + col] = f2bu(fmaxf(v, 0.f));
                } else if (EPI == 1) {
                    out0[(size_t)row * ldo0 + col] = f2bu(v);
                } else {
                    out0[(size_t)row * ldo0 + col] = f2bu(fmaxf(v + bias[col], 0.f));
                }
            }
        }
    }
}

// ---- weight transpose+convert: Wt[n][k] = (n<300 && k<Ks) ? W[k][n] : 0 ----
__global__ __launch_bounds__(256) void wconv_k(const float* __restrict__ W, int Ks, int Kp,
                                               u16* __restrict__ Wt)
{
    const int id = blockIdx.x * 256 + threadIdx.x;
    if (id >= NPAD * Kp) return;
    const int n = id / Kp, k = id - n * Kp;
    const float v = (n < HIDDEN && k < Ks) ? W[(size_t)k * HIDDEN + n] : 0.f;
    Wt[id] = f2bu(v);
}

// ---- f_bonds f32 -> bf16 padded [200000][160] ----
__global__ __launch_bounds__(256) void fbconv_k(const float* __restrict__ fb, u16* __restrict__ dst)
{
    const int id = blockIdx.x * 256 + threadIdx.x;
    if (id >= N_BONDS * KP_I) return;
    const int r = id / KP_I, k = id - r * KP_I;
    dst[id] = f2bu(k < BOND_FDIM ? fb[(size_t)r * BOND_FDIM + k] : 0.f);
}

// ---- dst[a][:] = sum_j src[a2b[a][j]][:]   (16B chunks, stride LDA) ----
__global__ __launch_bounds__(256) void agg_k(const u16* __restrict__ src,
                                             const int* __restrict__ a2b,
                                             u16* __restrict__ dst)
{
    const int c = blockIdx.x * 256 + threadIdx.x;
    if (c >= N_ATOMS * CPR) return;
    const int a = c / CPR, q = c - a * CPR;
    const int h = q * 8;
    const int* nb = a2b + (size_t)a * MAX_NB;
    float s[8] = {};
    #pragma unroll
    for (int j = 0; j < MAX_NB; ++j) {
        const int r = nb[j];
        union { uint4 u; u16 s[8]; } x;
        x.u = *(const uint4*)(src + (size_t)r * LDA + h);
        #pragma unroll
        for (int e = 0; e < 8; ++e) s[e] += bu2f(x.s[e]);
    }
    union { uint4 u; u16 s[8]; } o;
    #pragma unroll
    for (int e = 0; e < 8; ++e) o.s[e] = f2bu(s[e]);
    *(uint4*)(dst + (size_t)a * LDA + h) = o.u;
}

// ---- msg[b] = relu(inp[b] + aY[b2a[b]] - Y[b2revb[b]])   (16B chunks) ----
__global__ __launch_bounds__(256) void comb_k(const u16* __restrict__ inp,
                                              const u16* __restrict__ aY,
                                              const u16* __restrict__ Y,
                                              const int* __restrict__ b2a,
                                              const int* __restrict__ b2revb,
                                              u16* __restrict__ msg)
{
    const int c = blockIdx.x * 256 + threadIdx.x;
    if (c >= N_BONDS * CPR) return;
    const int b = c / CPR, q = c - b * CPR;
    const int h = q * 8;
    const int ia = b2a[b], ir = b2revb[b];
    union { uint4 u; u16 s[8]; } xi, xa, xy, o;
    xi.u = *(const uint4*)(inp + (size_t)b * LDA + h);
    xa.u = *(const uint4*)(aY + (size_t)ia * LDA + h);
    xy.u = *(const uint4*)(Y + (size_t)ir * LDA + h);
    #pragma unroll
    for (int j = 0; j < 8; ++j)
        o.s[j] = f2bu(fmaxf(bu2f(xi.s[j]) + bu2f(xa.s[j]) - bu2f(xy.s[j]), 0.f));
    *(uint4*)(msg + (size_t)b * LDA + h) = o.u;
}

// ---- concat[a][k] : k<133 f_atoms | k<433 amsg | 0 ----
__global__ __launch_bounds__(256) void concat_k(const float* __restrict__ fa,
                                                const u16* __restrict__ amsg,
                                                u16* __restrict__ dst)
{
    const int id = blockIdx.x * 256 + threadIdx.x;
    if (id >= N_ATOMS * KP_O) return;
    const int a = id / KP_O, k = id - a * KP_O;
    float v;
    if (k < ATOM_FDIM)                 v = fa[(size_t)a * ATOM_FDIM + k];
    else if (k < ATOM_FDIM + HIDDEN)   v = bu2f(amsg[(size_t)a * LDA + (k - ATOM_FDIM)]);
    else                               v = 0.f;
    dst[id] = f2bu(v);
}

// ---- per-mol mean over sorted atom2mol ----
__global__ __launch_bounds__(320) void pool_k(const u16* __restrict__ ah,
                                              const int* __restrict__ a2m,
                                              float* __restrict__ out)
{
    const int m = blockIdx.x;
    int lo, hi;
    { int l = 0, r = N_ATOMS;
      while (l < r) { int mid = (l + r) >> 1; if (a2m[mid] < m) l = mid + 1; else r = mid; }
      lo = l; }
    { int l = lo, r = N_ATOMS;
      while (l < r) { int mid = (l + r) >> 1; if (a2m[mid] < m + 1) l = mid + 1; else r = mid; }
      hi = l; }
    const float inv = 1.0f / (float)((hi - lo) > 1 ? (hi - lo) : 1);
    const int h = threadIdx.x;
    if (h >= HIDDEN) return;
    float s = 0.f;
    for (int a = lo; a < hi; ++a) s += bu2f(ah[(size_t)a * LDA + h]);
    out[(size_t)m * HIDDEN + h] = s * inv;
}

extern "C" void kernel_launch(void* const* d_in, const int* in_sizes, int n_in,
                              void* d_out, int out_size, void* d_ws, size_t ws_size,
                              hipStream_t stream)
{
    const float* f_atoms  = (const float*)d_in[0];
    const float* f_bonds  = (const float*)d_in[1];
    const int*   a2b      = (const int*)d_in[2];
    const int*   b2a      = (const int*)d_in[3];
    const int*   b2revb   = (const int*)d_in[4];
    const int*   atom2mol = (const int*)d_in[5];
    const float* W_i      = (const float*)d_in[6];
    const float* W_h      = (const float*)d_in[7];
    const float* W_o_w    = (const float*)d_in[8];
    const float* W_o_b    = (const float*)d_in[9];
    float* out = (float*)d_out;

    // ---- workspace layout (all bf16 as u16); +16 rows slack per big buffer ----
    char* p = (char*)d_ws;
    auto alloc = [&](size_t bytes) { char* r = p; p += (bytes + 255) & ~(size_t)255; return r; };
    u16* inp = (u16*)alloc(((size_t)N_BONDS + 16) * LDA * 2);   // 121.6 MB
    u16* msg = (u16*)alloc(((size_t)N_BONDS + 16) * LDA * 2);   // 121.6 MB
    u16* Yb  = (u16*)alloc(((size_t)N_BONDS + 16) * LDA * 2);   // 121.6 MB; hosts fb16/concat too
    u16* aY  = (u16*)alloc(((size_t)N_ATOMS + 16) * LDA * 2);   //  60.8 MB
    u16* Wti = (u16*)alloc((size_t)NPAD * KP_I * 2);
    u16* Wth = (u16*)alloc((size_t)NPAD * KP_H * 2);
    u16* Wto = (u16*)alloc((size_t)NPAD * KP_O * 2 + 4096);
    if ((size_t)(p - (char*)d_ws) > ws_size) return;

    u16* fb16   = Yb;   // [200000][160], dead before first Y write
    u16* concat = Yb;   // [100000][448], built after Y dead
    u16* ah     = msg;  // [100000][LDA], msg dead after final agg

    const dim3 blk(256);
    auto g1 = [](long long n) { return dim3((unsigned)((n + 255) / 256)); };
    const dim3 gB((N_BONDS + 63) / 64);   // 3125
    const dim3 gA((N_ATOMS + 63) / 64);   // 1563

    wconv_k<<<g1((long long)NPAD * KP_I), blk, 0, stream>>>(W_i, BOND_FDIM, KP_I, Wti);
    wconv_k<<<g1((long long)NPAD * KP_H), blk, 0, stream>>>(W_h, HIDDEN, KP_H, Wth);
    wconv_k<<<g1((long long)NPAD * KP_O), blk, 0, stream>>>(W_o_w, ATOM_FDIM + HIDDEN, KP_O, Wto);
    fbconv_k<<<g1((long long)N_BONDS * KP_I), blk, 0, stream>>>(f_bonds, fb16);

    // inp = f_bonds @ W_i ; msg = relu(inp)
    mm_k<0><<<gB, blk, 0, stream>>>(fb16, KP_I, Wti, KP_I, nullptr,
                                    inp, LDA, msg, LDA, N_BONDS, KP_I);

    for (int it = 0; it < 2; ++it) {   // DEPTH-1
        mm_k<1><<<gB, blk, 0, stream>>>(msg, LDA, Wth, KP_H, nullptr,
                                        Yb, LDA, nullptr, 0, N_BONDS, KP_H);
        agg_k<<<g1((long long)N_ATOMS * CPR), blk, 0, stream>>>(Yb, a2b, aY);
        comb_k<<<g1((long long)N_BONDS * CPR), blk, 0, stream>>>(inp, aY, Yb, b2a, b2revb, msg);
    }

    agg_k<<<g1((long long)N_ATOMS * CPR), blk, 0, stream>>>(msg, a2b, aY);
    concat_k<<<g1((long long)N_ATOMS * KP_O), blk, 0, stream>>>(f_atoms, aY, concat);
    mm_k<2><<<gA, blk, 0, stream>>>(concat, KP_O, Wto, KP_O, W_o_b,
                                    ah, LDA, nullptr, 0, N_ATOMS, KP_O);
    pool_k<<<dim3(N_MOLS), dim3(320), 0, stream>>>(ah, atom2mol, out);
}

// Round 4
// 1000.424 us; speedup vs baseline: 3.4397x; 1.0134x over previous
//
#include <hip/hip_runtime.h>
#include <stdint.h>

#define ATOM_FDIM 133
#define BOND_FDIM 147
#define HIDDEN    300
#define N_ATOMS   100000
#define N_BONDS   200000
#define MAX_NB    6
#define N_MOLS    4000

#define NPAD 320      // padded N for all GEMMs
#define KP_I 160      // padded K for W_i GEMM (147)
#define KP_H 320      // padded K for W_h GEMM (300)
#define KP_O 448      // padded K for W_o GEMM (433)
#define LDA  304      // activation row stride in elems (608B, 16B-aligned)
#define CPR  38       // uint4 chunks per activation row (304/8)

typedef unsigned short u16;
typedef short bf16x8 __attribute__((ext_vector_type(8)));
typedef float f32x4 __attribute__((ext_vector_type(4)));

__device__ __forceinline__ u16 f2bu(float f) {            // f32 -> bf16 (RNE)
    unsigned u = __float_as_uint(f);
    u += 0x7FFFu + ((u >> 16) & 1u);
    return (u16)(u >> 16);
}
__device__ __forceinline__ float bu2f(u16 b) { return __uint_as_float(((unsigned)b) << 16); }

#define AS1 __attribute__((address_space(1)))
#define AS3 __attribute__((address_space(3)))
__device__ __forceinline__ void gl_lds16(const void* g, void* l) {
    __builtin_amdgcn_global_load_lds((const AS1 void*)g, (AS3 void*)l, 16, 0, 0);
}

// ------------- dense bf16 MFMA GEMM, full-N tile: C[64 x 300] per block ---------------
// Block: 64 rows x 320 cols. 4 waves 2x2; wave = 32 rows x 160 cols = 2x10 frags.
// Double-buffered LDS, counted vmcnt(6) (1 A + 5 B stages per wave per K-step),
// raw s_barrier (no vmcnt(0) drain). LDS is fragment-ordered via pre-swizzled
// global source, so every frag read is a contiguous per-wave ds_read_b128.
// EPI 0: out0=raw, out1=relu | EPI 1: out0=raw | EPI 2: out0=relu(v+bias)
template <int EPI>
__global__ __launch_bounds__(256, 3) void mm_k(
    const u16* __restrict__ A, int lda,
    const u16* __restrict__ Wt, int ldw,
    const float* __restrict__ bias,
    u16* __restrict__ out0, int ldo0,
    u16* __restrict__ out1, int ldo1,
    int M, int NT)                      // NT = Kp/32 K-steps
{
    __shared__ __align__(16) u16 As[2][64 * 32];    // 2 x 4 KB
    __shared__ __align__(16) u16 Bs[2][320 * 32];   // 2 x 20 KB

    const int t    = threadIdx.x;
    const int lane = t & 63, wid = t >> 6;
    const int fl   = lane & 15, fh = lane >> 4;
    const int m0   = blockIdx.x * 64;
    const int wr   = wid >> 1, wc = wid & 1;

    // staging sources (pre-swizzled so LDS ends up fragment-ordered)
    int arow = m0 + wid * 16 + fl;
    if (arow > M - 1) arow = M - 1;
    const unsigned offA = (unsigned)arow * (unsigned)lda * 2u + (unsigned)fh * 16u;
    unsigned offB[5];
    #pragma unroll
    for (int j = 0; j < 5; ++j)
        offB[j] = (unsigned)((wid + 4 * j) * 16 + fl) * (unsigned)ldw * 2u + (unsigned)fh * 16u;

    f32x4 acc[2][10] = {};

    // prologue: stage tile 0 into buf 0
    {
        gl_lds16((const char*)A + (size_t)offA, (char*)&As[0][wid * 512]);
        #pragma unroll
        for (int j = 0; j < 5; ++j)
            gl_lds16((const char*)Wt + (size_t)offB[j], (char*)&Bs[0][(wid + 4 * j) * 512]);
    }

    for (int tt = 0; tt < NT; ++tt) {
        const int cur = tt & 1, nxt = cur ^ 1;
        // issue prefetch of tile tt+1 (modular restage of tile 0 on last iter
        // keeps the vmcnt immediate a compile-time constant)
        const unsigned kb = (tt + 1 < NT) ? (unsigned)(tt + 1) * 64u : 0u;
        gl_lds16((const char*)A + (size_t)(offA + kb), (char*)&As[nxt][wid * 512]);
        #pragma unroll
        for (int j = 0; j < 5; ++j)
            gl_lds16((const char*)Wt + (size_t)(offB[j] + kb), (char*)&Bs[nxt][(wid + 4 * j) * 512]);

        // wait for tile tt only (the 6 just-issued stay in flight)
        asm volatile("s_waitcnt vmcnt(6)" ::: "memory");
        __builtin_amdgcn_s_barrier();

        bf16x8 af[2], bfv[10];
        #pragma unroll
        for (int m = 0; m < 2; ++m)
            af[m] = *reinterpret_cast<const bf16x8*>(&As[cur][(wr * 2 + m) * 512 + lane * 8]);
        #pragma unroll
        for (int n = 0; n < 10; ++n)
            bfv[n] = *reinterpret_cast<const bf16x8*>(&Bs[cur][(wc * 10 + n) * 512 + lane * 8]);
        #pragma unroll
        for (int m = 0; m < 2; ++m)
            #pragma unroll
            for (int n = 0; n < 10; ++n)
                acc[m][n] = __builtin_amdgcn_mfma_f32_16x16x32_bf16(af[m], bfv[n], acc[m][n], 0, 0, 0);

        // WAR guard: all waves done reading buf[cur] before next iter stages into it
        __builtin_amdgcn_s_barrier();
    }

    // epilogue: C/D col=lane&15, row=(lane>>4)*4+reg
    #pragma unroll
    for (int m = 0; m < 2; ++m) {
        #pragma unroll
        for (int r = 0; r < 4; ++r) {
            const int row = m0 + wr * 32 + m * 16 + fh * 4 + r;
            if (row >= M) continue;
            #pragma unroll
            for (int n = 0; n < 10; ++n) {
                const int col = wc * 160 + n * 16 + fl;
                if (col >= HIDDEN) continue;
                const float v = acc[m][n][r];
                if (EPI == 0) {
                    out0[(size_t)row * ldo0 + col] = f2bu(v);
                    out1[(size_t)row * ldo1 + col] = f2bu(fmaxf(v, 0.f));
                } else if (EPI == 1) {
                    out0[(size_t)row * ldo0 + col] = f2bu(v);
                } else {
                    out0[(size_t)row * ldo0 + col] = f2bu(fmaxf(v + bias[col], 0.f));
                }
            }
        }
    }
}

// ---- weight transpose+convert: Wt[n][k] = (n<300 && k<Ks) ? W[k][n] : 0 ----
__global__ __launch_bounds__(256) void wconv_k(const float* __restrict__ W, int Ks, int Kp,
                                               u16* __restrict__ Wt)
{
    const int id = blockIdx.x * 256 + threadIdx.x;
    if (id >= NPAD * Kp) return;
    const int n = id / Kp, k = id - n * Kp;
    const float v = (n < HIDDEN && k < Ks) ? W[(size_t)k * HIDDEN + n] : 0.f;
    Wt[id] = f2bu(v);
}

// ---- f_bonds f32 -> bf16 padded [200000][160] ----
__global__ __launch_bounds__(256) void fbconv_k(const float* __restrict__ fb, u16* __restrict__ dst)
{
    const int id = blockIdx.x * 256 + threadIdx.x;
    if (id >= N_BONDS * KP_I) return;
    const int r = id / KP_I, k = id - r * KP_I;
    dst[id] = f2bu(k < BOND_FDIM ? fb[(size_t)r * BOND_FDIM + k] : 0.f);
}

// ---- dst[a][:] = sum_j src[a2b[a][j]][:]   (16B chunks, stride LDA) ----
__global__ __launch_bounds__(256) void agg_k(const u16* __restrict__ src,
                                             const int* __restrict__ a2b,
                                             u16* __restrict__ dst)
{
    const int c = blockIdx.x * 256 + threadIdx.x;
    if (c >= N_ATOMS * CPR) return;
    const int a = c / CPR, q = c - a * CPR;
    const int h = q * 8;
    const int* nb = a2b + (size_t)a * MAX_NB;
    float s[8] = {};
    #pragma unroll
    for (int j = 0; j < MAX_NB; ++j) {
        const int r = nb[j];
        union { uint4 u; u16 s[8]; } x;
        x.u = *(const uint4*)(src + (size_t)r * LDA + h);
        #pragma unroll
        for (int e = 0; e < 8; ++e) s[e] += bu2f(x.s[e]);
    }
    union { uint4 u; u16 s[8]; } o;
    #pragma unroll
    for (int e = 0; e < 8; ++e) o.s[e] = f2bu(s[e]);
    *(uint4*)(dst + (size_t)a * LDA + h) = o.u;
}

// ---- msg[b] = relu(inp[b] + aY[b2a[b]] - Y[b2revb[b]])   (16B chunks) ----
__global__ __launch_bounds__(256) void comb_k(const u16* __restrict__ inp,
                                              const u16* __restrict__ aY,
                                              const u16* __restrict__ Y,
                                              const int* __restrict__ b2a,
                                              const int* __restrict__ b2revb,
                                              u16* __restrict__ msg)
{
    const int c = blockIdx.x * 256 + threadIdx.x;
    if (c >= N_BONDS * CPR) return;
    const int b = c / CPR, q = c - b * CPR;
    const int h = q * 8;
    const int ia = b2a[b], ir = b2revb[b];
    union { uint4 u; u16 s[8]; } xi, xa, xy, o;
    xi.u = *(const uint4*)(inp + (size_t)b * LDA + h);
    xa.u = *(const uint4*)(aY + (size_t)ia * LDA + h);
    xy.u = *(const uint4*)(Y + (size_t)ir * LDA + h);
    #pragma unroll
    for (int j = 0; j < 8; ++j)
        o.s[j] = f2bu(fmaxf(bu2f(xi.s[j]) + bu2f(xa.s[j]) - bu2f(xy.s[j]), 0.f));
    *(uint4*)(msg + (size_t)b * LDA + h) = o.u;
}

// ---- concat[a][k] : k<133 f_atoms | k<433 amsg | 0 ----
__global__ __launch_bounds__(256) void concat_k(const float* __restrict__ fa,
                                                const u16* __restrict__ amsg,
                                                u16* __restrict__ dst)
{
    const int id = blockIdx.x * 256 + threadIdx.x;
    if (id >= N_ATOMS * KP_O) return;
    const int a = id / KP_O, k = id - a * KP_O;
    float v;
    if (k < ATOM_FDIM)                 v = fa[(size_t)a * ATOM_FDIM + k];
    else if (k < ATOM_FDIM + HIDDEN)   v = bu2f(amsg[(size_t)a * LDA + (k - ATOM_FDIM)]);
    else                               v = 0.f;
    dst[id] = f2bu(v);
}

// ---- per-mol mean over sorted atom2mol ----
__global__ __launch_bounds__(320) void pool_k(const u16* __restrict__ ah,
                                              const int* __restrict__ a2m,
                                              float* __restrict__ out)
{
    const int m = blockIdx.x;
    int lo, hi;
    { int l = 0, r = N_ATOMS;
      while (l < r) { int mid = (l + r) >> 1; if (a2m[mid] < m) l = mid + 1; else r = mid; }
      lo = l; }
    { int l = lo, r = N_ATOMS;
      while (l < r) { int mid = (l + r) >> 1; if (a2m[mid] < m + 1) l = mid + 1; else r = mid; }
      hi = l; }
    const float inv = 1.0f / (float)((hi - lo) > 1 ? (hi - lo) : 1);
    const int h = threadIdx.x;
    if (h >= HIDDEN) return;
    float s = 0.f;
    for (int a = lo; a < hi; ++a) s += bu2f(ah[(size_t)a * LDA + h]);
    out[(size_t)m * HIDDEN + h] = s * inv;
}

extern "C" void kernel_launch(void* const* d_in, const int* in_sizes, int n_in,
                              void* d_out, int out_size, void* d_ws, size_t ws_size,
                              hipStream_t stream)
{
    const float* f_atoms  = (const float*)d_in[0];
    const float* f_bonds  = (const float*)d_in[1];
    const int*   a2b      = (const int*)d_in[2];
    const int*   b2a      = (const int*)d_in[3];
    const int*   b2revb   = (const int*)d_in[4];
    const int*   atom2mol = (const int*)d_in[5];
    const float* W_i      = (const float*)d_in[6];
    const float* W_h      = (const float*)d_in[7];
    const float* W_o_w    = (const float*)d_in[8];
    const float* W_o_b    = (const float*)d_in[9];
    float* out = (float*)d_out;

    // ---- workspace layout (all bf16 as u16); +16 rows slack per big buffer ----
    char* p = (char*)d_ws;
    auto alloc = [&](size_t bytes) { char* r = p; p += (bytes + 255) & ~(size_t)255; return r; };
    u16* inp = (u16*)alloc(((size_t)N_BONDS + 16) * LDA * 2);   // 121.6 MB
    u16* msg = (u16*)alloc(((size_t)N_BONDS + 16) * LDA * 2);   // 121.6 MB
    u16* Yb  = (u16*)alloc(((size_t)N_BONDS + 16) * LDA * 2);   // 121.6 MB; hosts fb16/concat too
    u16* aY  = (u16*)alloc(((size_t)N_ATOMS + 16) * LDA * 2);   //  60.8 MB
    u16* Wti = (u16*)alloc((size_t)NPAD * KP_I * 2);
    u16* Wth = (u16*)alloc((size_t)NPAD * KP_H * 2);
    u16* Wto = (u16*)alloc((size_t)NPAD * KP_O * 2 + 4096);
    if ((size_t)(p - (char*)d_ws) > ws_size) return;

    u16* fb16   = Yb;   // [200000][160], dead before first Y write
    u16* concat = Yb;   // [100000][448], built after Y dead
    u16* ah     = msg;  // [100000][LDA], msg dead after final agg

    const dim3 blk(256);
    auto g1 = [](long long n) { return dim3((unsigned)((n + 255) / 256)); };
    const dim3 gB((N_BONDS + 63) / 64);   // 3125
    const dim3 gA((N_ATOMS + 63) / 64);   // 1563

    wconv_k<<<g1((long long)NPAD * KP_I), blk, 0, stream>>>(W_i, BOND_FDIM, KP_I, Wti);
    wconv_k<<<g1((long long)NPAD * KP_H), blk, 0, stream>>>(W_h, HIDDEN, KP_H, Wth);
    wconv_k<<<g1((long long)NPAD * KP_O), blk, 0, stream>>>(W_o_w, ATOM_FDIM + HIDDEN, KP_O, Wto);
    fbconv_k<<<g1((long long)N_BONDS * KP_I), blk, 0, stream>>>(f_bonds, fb16);

    // inp = f_bonds @ W_i ; msg = relu(inp)
    mm_k<0><<<gB, blk, 0, stream>>>(fb16, KP_I, Wti, KP_I, nullptr,
                                    inp, LDA, msg, LDA, N_BONDS, KP_I / 32);

    for (int it = 0; it < 2; ++it) {   // DEPTH-1
        mm_k<1><<<gB, blk, 0, stream>>>(msg, LDA, Wth, KP_H, nullptr,
                                        Yb, LDA, nullptr, 0, N_BONDS, KP_H / 32);
        agg_k<<<g1((long long)N_ATOMS * CPR), blk, 0, stream>>>(Yb, a2b, aY);
        comb_k<<<g1((long long)N_BONDS * CPR), blk, 0, stream>>>(inp, aY, Yb, b2a, b2revb, msg);
    }

    agg_k<<<g1((long long)N_ATOMS * CPR), blk, 0, stream>>>(msg, a2b, aY);
    concat_k<<<g1((long long)N_ATOMS * KP_O), blk, 0, stream>>>(f_atoms, aY, concat);
    mm_k<2><<<gA, blk, 0, stream>>>(concat, KP_O, Wto, KP_O, W_o_b,
                                    ah, LDA, nullptr, 0, N_ATOMS, KP_O / 32);
    pool_k<<<dim3(N_MOLS), dim3(320), 0, stream>>>(ah, atom2mol, out);
}

// Round 5
// 945.383 us; speedup vs baseline: 3.6399x; 1.0582x over previous
//
#include <hip/hip_runtime.h>
#include <stdint.h>

#define ATOM_FDIM 133
#define BOND_FDIM 147
#define HIDDEN    300
#define N_ATOMS   100000
#define N_BONDS   200000
#define MAX_NB    6
#define N_MOLS    4000

#define KP_I 160      // padded K for W_i GEMM (147)
#define KP_H 320      // padded K for W_h GEMM (300)
#define KP_O 448      // padded K for W_o GEMM (433)
#define LDA  304      // activation row stride in elems (608B, 16B-aligned)
#define CPR  38       // uint4 chunks per activation row (304/8)

#define TM   128      // GEMM tile rows
#define NPAD 384      // GEMM tile cols (padded N, uniform staging)
#define ACH  8        // A chunks (1KB) per K-tile
#define BCH  24       // B chunks (1KB) per K-tile

typedef unsigned short u16;
typedef short bf16x8 __attribute__((ext_vector_type(8)));
typedef float f32x4 __attribute__((ext_vector_type(4)));

__device__ __forceinline__ u16 f2bu(float f) {            // f32 -> bf16 (RNE)
    unsigned u = __float_as_uint(f);
    u += 0x7FFFu + ((u >> 16) & 1u);
    return (u16)(u >> 16);
}
__device__ __forceinline__ float bu2f(u16 b) { return __uint_as_float(((unsigned)b) << 16); }

#define AS1 __attribute__((address_space(1)))
#define AS3 __attribute__((address_space(3)))
__device__ __forceinline__ void gl_lds16(const void* g, void* l) {
    __builtin_amdgcn_global_load_lds((const AS1 void*)g, (AS3 void*)l, 16, 0, 0);
}

// ---------- dense bf16 MFMA GEMM, phase-split tri-buffered pipeline ----------
// Block: 128 rows x 384 cols, 512 threads (8 waves, 4x2). Wave: 32 rows x 192
// cols = 2x12 frags of 16x16x32. LDS: 3 bufs x (A 8KB + B 24KB) = 96KB.
// Per K-step (BK=32): 2 sub-phases, 4 barriers, counted vmcnt(4) (never 0 in
// loop), setprio around MFMA clusters. B is staged from contiguous 1KB panels.
// EPI 0: out0=raw, out1=relu | EPI 1: out0=raw | EPI 2: out0=relu(v+bias)
template <int EPI>
__global__ __launch_bounds__(512, 2) void mm_k(
    const u16* __restrict__ A, int lda,
    const u16* __restrict__ Wp,          // panel layout: [NT][BCH][512] elems
    const float* __restrict__ bias,
    u16* __restrict__ out0, int ldo0,
    u16* __restrict__ out1, int ldo1,
    int M, int NT)                       // NT = Kp/32 K-steps
{
    __shared__ __align__(16) u16 As[3][ACH * 512];   // 3 x 8 KB
    __shared__ __align__(16) u16 Bs[3][BCH * 512];   // 3 x 24 KB

    const int t    = threadIdx.x;
    const int lane = t & 63, wid = t >> 6;
    const int fl   = lane & 15, fh = lane >> 4;
    const int m0   = blockIdx.x * TM;
    const int wr   = wid >> 1, wc = wid & 1;

    // A stage source: wave w covers rows [w*16, w*16+16); lane l -> row base+(l&15),
    // 16B at k-seg (l>>4). Pre-swizzled so LDS slot order == fragment order.
    int arow = m0 + wid * 16 + fl;
    if (arow > M - 1) arow = M - 1;
    const size_t srcA = (size_t)arow * (size_t)lda * 2u + (size_t)(fh * 16);
    // B stage source: contiguous 1KB panels; wave w stages chunks 3w..3w+2.
    const size_t srcB = (size_t)(3 * wid) * 1024u + (size_t)lane * 16u;

    char* ldsA_of[3] = { (char*)As[0] + wid * 1024, (char*)As[1] + wid * 1024,
                         (char*)As[2] + wid * 1024 };
    char* ldsB_of[3] = { (char*)Bs[0] + 3 * wid * 1024, (char*)Bs[1] + 3 * wid * 1024,
                         (char*)Bs[2] + 3 * wid * 1024 };

    f32x4 acc[2][12] = {};

    // prologue: stage tiles 0 and 1 (4 loads each per wave)
    {
        gl_lds16((const char*)A + srcA, ldsA_of[0]);
        #pragma unroll
        for (int j = 0; j < 3; ++j)
            gl_lds16((const char*)Wp + srcB + (size_t)j * 1024, ldsB_of[0] + j * 1024);
        gl_lds16((const char*)A + srcA + 64, ldsA_of[1]);
        #pragma unroll
        for (int j = 0; j < 3; ++j)
            gl_lds16((const char*)Wp + (size_t)BCH * 1024 + srcB + (size_t)j * 1024,
                     ldsB_of[1] + j * 1024);
    }
    asm volatile("s_waitcnt vmcnt(4)" ::: "memory");   // tile 0 landed
    __builtin_amdgcn_s_barrier();

    int cur = 0;
    for (int tt = 0; tt < NT; ++tt) {
        const int nx2 = (cur >= 1) ? cur - 1 : 2;      // (cur+2)%3
        int w2 = tt + 2; if (w2 >= NT) w2 -= NT;       // wrapped prefetch tile
        const u16* as_c = As[cur];
        const u16* bs_c = Bs[cur];
        const size_t kbA = (size_t)w2 * 64u;
        const size_t kbB = (size_t)w2 * (BCH * 1024u);

        bf16x8 af0, af1, bfv[12];

        // ---------- phase 1 ----------
        af0 = *reinterpret_cast<const bf16x8*>(&as_c[(wr * 2 + 0) * 512 + lane * 8]);
        af1 = *reinterpret_cast<const bf16x8*>(&as_c[(wr * 2 + 1) * 512 + lane * 8]);
        #pragma unroll
        for (int n = 0; n < 6; ++n)
            bfv[n] = *reinterpret_cast<const bf16x8*>(&bs_c[(wc * 12 + n) * 512 + lane * 8]);
        gl_lds16((const char*)A + srcA + kbA, ldsA_of[nx2]);
        gl_lds16((const char*)Wp + kbB + srcB, ldsB_of[nx2]);
        __builtin_amdgcn_s_barrier();
        __builtin_amdgcn_s_setprio(1);
        #pragma unroll
        for (int n = 0; n < 6; ++n) {
            acc[0][n] = __builtin_amdgcn_mfma_f32_16x16x32_bf16(af0, bfv[n], acc[0][n], 0, 0, 0);
            acc[1][n] = __builtin_amdgcn_mfma_f32_16x16x32_bf16(af1, bfv[n], acc[1][n], 0, 0, 0);
        }
        __builtin_amdgcn_s_setprio(0);
        __builtin_amdgcn_s_barrier();

        // ---------- phase 2 ----------
        #pragma unroll
        for (int n = 6; n < 12; ++n)
            bfv[n] = *reinterpret_cast<const bf16x8*>(&bs_c[(wc * 12 + n) * 512 + lane * 8]);
        gl_lds16((const char*)Wp + kbB + srcB + 1024, ldsB_of[nx2] + 1024);
        gl_lds16((const char*)Wp + kbB + srcB + 2048, ldsB_of[nx2] + 2048);
        // gate: tile tt+1's 4 loads (oldest) retired; tile tt+2's 4 stay in flight
        asm volatile("s_waitcnt vmcnt(4)" ::: "memory");
        __builtin_amdgcn_s_barrier();
        __builtin_amdgcn_s_setprio(1);
        #pragma unroll
        for (int n = 6; n < 12; ++n) {
            acc[0][n] = __builtin_amdgcn_mfma_f32_16x16x32_bf16(af0, bfv[n], acc[0][n], 0, 0, 0);
            acc[1][n] = __builtin_amdgcn_mfma_f32_16x16x32_bf16(af1, bfv[n], acc[1][n], 0, 0, 0);
        }
        __builtin_amdgcn_s_setprio(0);
        __builtin_amdgcn_s_barrier();

        cur = (cur == 2) ? 0 : cur + 1;
    }

    // epilogue: C/D col=lane&15, row=(lane>>4)*4+reg
    #pragma unroll
    for (int m = 0; m < 2; ++m) {
        #pragma unroll
        for (int r = 0; r < 4; ++r) {
            const int row = m0 + wr * 32 + m * 16 + fh * 4 + r;
            if (row >= M) continue;
            #pragma unroll
            for (int n = 0; n < 12; ++n) {
                const int col = wc * 192 + n * 16 + fl;
                if (col >= HIDDEN) continue;
                const float v = acc[m][n][r];
                if (EPI == 0) {
                    out0[(size_t)row * ldo0 + col] = f2bu(v);
                    out1[(size_t)row * ldo1 + col] = f2bu(fmaxf(v, 0.f));
                } else if (EPI == 1) {
                    out0[(size_t)row * ldo0 + col] = f2bu(v);
                } else {
                    out0[(size_t)row * ldo0 + col] = f2bu(fmaxf(v + bias[col], 0.f));
                }
            }
        }
    }
}

// ---- weight -> staged panel layout: Wp[kt][c][l][e] with
//      col = c*16 + (l&15), k = kt*32 + (l>>4)*8 + e ----
__global__ __launch_bounds__(256) void wconv_k(const float* __restrict__ W, int Ks, int NT,
                                               u16* __restrict__ Wp)
{
    const int id = blockIdx.x * 256 + threadIdx.x;
    if (id >= NT * BCH * 512) return;
    const int block = id >> 9, rem = id & 511;
    const int l = rem >> 3, e = rem & 7;
    const int c = block % BCH, kt = block / BCH;
    const int col = c * 16 + (l & 15);
    const int k   = kt * 32 + (l >> 4) * 8 + e;
    const float v = (col < HIDDEN && k < Ks) ? W[(size_t)k * HIDDEN + col] : 0.f;
    Wp[id] = f2bu(v);
}

// ---- f_bonds f32 -> bf16 padded [200000][160] ----
__global__ __launch_bounds__(256) void fbconv_k(const float* __restrict__ fb, u16* __restrict__ dst)
{
    const int id = blockIdx.x * 256 + threadIdx.x;
    if (id >= N_BONDS * KP_I) return;
    const int r = id / KP_I, k = id - r * KP_I;
    dst[id] = f2bu(k < BOND_FDIM ? fb[(size_t)r * BOND_FDIM + k] : 0.f);
}

// ---- dst[a][:] = sum_j src[a2b[a][j]][:]   (16B chunks, stride LDA) ----
__global__ __launch_bounds__(256) void agg_k(const u16* __restrict__ src,
                                             const int* __restrict__ a2b,
                                             u16* __restrict__ dst)
{
    const int c = blockIdx.x * 256 + threadIdx.x;
    if (c >= N_ATOMS * CPR) return;
    const int a = c / CPR, q = c - a * CPR;
    const int h = q * 8;
    const int* nb = a2b + (size_t)a * MAX_NB;
    float s[8] = {};
    #pragma unroll
    for (int j = 0; j < MAX_NB; ++j) {
        const int r = nb[j];
        union { uint4 u; u16 s[8]; } x;
        x.u = *(const uint4*)(src + (size_t)r * LDA + h);
        #pragma unroll
        for (int e = 0; e < 8; ++e) s[e] += bu2f(x.s[e]);
    }
    union { uint4 u; u16 s[8]; } o;
    #pragma unroll
    for (int e = 0; e < 8; ++e) o.s[e] = f2bu(s[e]);
    *(uint4*)(dst + (size_t)a * LDA + h) = o.u;
}

// ---- msg[b] = relu(inp[b] + aY[b2a[b]] - Y[b2revb[b]])   (16B chunks) ----
__global__ __launch_bounds__(256) void comb_k(const u16* __restrict__ inp,
                                              const u16* __restrict__ aY,
                                              const u16* __restrict__ Y,
                                              const int* __restrict__ b2a,
                                              const int* __restrict__ b2revb,
                                              u16* __restrict__ msg)
{
    const int c = blockIdx.x * 256 + threadIdx.x;
    if (c >= N_BONDS * CPR) return;
    const int b = c / CPR, q = c - b * CPR;
    const int h = q * 8;
    const int ia = b2a[b], ir = b2revb[b];
    union { uint4 u; u16 s[8]; } xi, xa, xy, o;
    xi.u = *(const uint4*)(inp + (size_t)b * LDA + h);
    xa.u = *(const uint4*)(aY + (size_t)ia * LDA + h);
    xy.u = *(const uint4*)(Y + (size_t)ir * LDA + h);
    #pragma unroll
    for (int j = 0; j < 8; ++j)
        o.s[j] = f2bu(fmaxf(bu2f(xi.s[j]) + bu2f(xa.s[j]) - bu2f(xy.s[j]), 0.f));
    *(uint4*)(msg + (size_t)b * LDA + h) = o.u;
}

// ---- concat[a][k] : k<133 f_atoms | k<433 amsg | 0 ----
__global__ __launch_bounds__(256) void concat_k(const float* __restrict__ fa,
                                                const u16* __restrict__ amsg,
                                                u16* __restrict__ dst)
{
    const int id = blockIdx.x * 256 + threadIdx.x;
    if (id >= N_ATOMS * KP_O) return;
    const int a = id / KP_O, k = id - a * KP_O;
    float v;
    if (k < ATOM_FDIM)                 v = fa[(size_t)a * ATOM_FDIM + k];
    else if (k < ATOM_FDIM + HIDDEN)   v = bu2f(amsg[(size_t)a * LDA + (k - ATOM_FDIM)]);
    else                               v = 0.f;
    dst[id] = f2bu(v);
}

// ---- per-mol mean over sorted atom2mol ----
__global__ __launch_bounds__(320) void pool_k(const u16* __restrict__ ah,
                                              const int* __restrict__ a2m,
                                              float* __restrict__ out)
{
    const int m = blockIdx.x;
    int lo, hi;
    { int l = 0, r = N_ATOMS;
      while (l < r) { int mid = (l + r) >> 1; if (a2m[mid] < m) l = mid + 1; else r = mid; }
      lo = l; }
    { int l = lo, r = N_ATOMS;
      while (l < r) { int mid = (l + r) >> 1; if (a2m[mid] < m + 1) l = mid + 1; else r = mid; }
      hi = l; }
    const float inv = 1.0f / (float)((hi - lo) > 1 ? (hi - lo) : 1);
    const int h = threadIdx.x;
    if (h >= HIDDEN) return;
    float s = 0.f;
    for (int a = lo; a < hi; ++a) s += bu2f(ah[(size_t)a * LDA + h]);
    out[(size_t)m * HIDDEN + h] = s * inv;
}

extern "C" void kernel_launch(void* const* d_in, const int* in_sizes, int n_in,
                              void* d_out, int out_size, void* d_ws, size_t ws_size,
                              hipStream_t stream)
{
    const float* f_atoms  = (const float*)d_in[0];
    const float* f_bonds  = (const float*)d_in[1];
    const int*   a2b      = (const int*)d_in[2];
    const int*   b2a      = (const int*)d_in[3];
    const int*   b2revb   = (const int*)d_in[4];
    const int*   atom2mol = (const int*)d_in[5];
    const float* W_i      = (const float*)d_in[6];
    const float* W_h      = (const float*)d_in[7];
    const float* W_o_w    = (const float*)d_in[8];
    const float* W_o_b    = (const float*)d_in[9];
    float* out = (float*)d_out;

    // ---- workspace layout (all bf16 as u16); +16 rows slack per big buffer ----
    char* p = (char*)d_ws;
    auto alloc = [&](size_t bytes) { char* r = p; p += (bytes + 255) & ~(size_t)255; return r; };
    u16* inp = (u16*)alloc(((size_t)N_BONDS + 16) * LDA * 2);   // 121.6 MB
    u16* msg = (u16*)alloc(((size_t)N_BONDS + 16) * LDA * 2);   // 121.6 MB
    u16* Yb  = (u16*)alloc(((size_t)N_BONDS + 16) * LDA * 2);   // 121.6 MB; hosts fb16/concat too
    u16* aY  = (u16*)alloc(((size_t)N_ATOMS + 16) * LDA * 2);   //  60.8 MB
    u16* Wpi = (u16*)alloc((size_t)(KP_I / 32) * BCH * 512 * 2);
    u16* Wph = (u16*)alloc((size_t)(KP_H / 32) * BCH * 512 * 2);
    u16* Wpo = (u16*)alloc((size_t)(KP_O / 32) * BCH * 512 * 2);
    if ((size_t)(p - (char*)d_ws) > ws_size) return;

    u16* fb16   = Yb;   // [200000][160], dead before first Y write
    u16* concat = Yb;   // [100000][448], built after Y dead
    u16* ah     = msg;  // [100000][LDA], msg dead after final agg

    const dim3 blk(256);
    auto g1 = [](long long n) { return dim3((unsigned)((n + 255) / 256)); };
    const dim3 blk5(512);
    const dim3 gB((N_BONDS + TM - 1) / TM);   // 1563
    const dim3 gA((N_ATOMS + TM - 1) / TM);   //  782

    wconv_k<<<g1((long long)(KP_I / 32) * BCH * 512), blk, 0, stream>>>(W_i, BOND_FDIM, KP_I / 32, Wpi);
    wconv_k<<<g1((long long)(KP_H / 32) * BCH * 512), blk, 0, stream>>>(W_h, HIDDEN, KP_H / 32, Wph);
    wconv_k<<<g1((long long)(KP_O / 32) * BCH * 512), blk, 0, stream>>>(W_o_w, ATOM_FDIM + HIDDEN, KP_O / 32, Wpo);
    fbconv_k<<<g1((long long)N_BONDS * KP_I), blk, 0, stream>>>(f_bonds, fb16);

    // inp = f_bonds @ W_i ; msg = relu(inp)
    mm_k<0><<<gB, blk5, 0, stream>>>(fb16, KP_I, Wpi, nullptr,
                                     inp, LDA, msg, LDA, N_BONDS, KP_I / 32);

    for (int it = 0; it < 2; ++it) {   // DEPTH-1
        mm_k<1><<<gB, blk5, 0, stream>>>(msg, LDA, Wph, nullptr,
                                         Yb, LDA, nullptr, 0, N_BONDS, KP_H / 32);
        agg_k<<<g1((long long)N_ATOMS * CPR), blk, 0, stream>>>(Yb, a2b, aY);
        comb_k<<<g1((long long)N_BONDS * CPR), blk, 0, stream>>>(inp, aY, Yb, b2a, b2revb, msg);
    }

    agg_k<<<g1((long long)N_ATOMS * CPR), blk, 0, stream>>>(msg, a2b, aY);
    concat_k<<<g1((long long)N_ATOMS * KP_O), blk, 0, stream>>>(f_atoms, aY, concat);
    mm_k<2><<<gA, blk5, 0, stream>>>(concat, KP_O, Wpo, W_o_b,
                                     ah, LDA, nullptr, 0, N_ATOMS, KP_O / 32);
    pool_k<<<dim3(N_MOLS), dim3(320), 0, stream>>>(ah, atom2mol, out);
}